// Round 3
// baseline (123.632 us; speedup 1.0000x reference)
//
#include <hip/hip_runtime.h>
#include <math.h>

#define NCLS 1784
#define NF4 446          // 1784 / 4
#define NBATCH 16384
#define NBLOCKS (NBATCH / 4)   // 4096
#define LOG2E 1.4426950408889634f

// One wave (64 lanes) per row; 4 rows per 256-thread block.
// Each block publishes one partial; the last-arriving block reduces all
// 4096 partials in fixed index order (bit-deterministic regardless of
// which block is last) and writes the final scalar.
__global__ __launch_bounds__(256) void cevp_fused_kernel(
        const float* __restrict__ logits,
        const int* __restrict__ targets,
        const float* __restrict__ P,
        float* __restrict__ ws,
        unsigned* __restrict__ counter,
        float* __restrict__ out) {
    const int wave = threadIdx.x >> 6;          // 0..3
    const int lane = threadIdx.x & 63;
    const int row  = blockIdx.x * 4 + wave;

    // Hoisted scattered loads: wave-uniform broadcast, latency overlaps the
    // bulk row loads below. Only P[tgt, argmax] stays on the dependent tail.
    const int   tgt = targets[row];
    const float lt  = logits[(size_t)row * NCLS + tgt];

    const float4* __restrict__ rp =
        reinterpret_cast<const float4*>(logits + (size_t)row * NCLS);

    // Whole row into registers: 7 float4 per lane (446 f4 per row).
    float4 v[7];
    #pragma unroll
    for (int k = 0; k < 7; ++k) {
        const int idx = lane + 64 * k;
        if (idx < NF4) {
            v[k] = rp[idx];
        } else {
            v[k] = make_float4(-INFINITY, -INFINITY, -INFINITY, -INFINITY);
        }
    }

    // Per-lane max + first-occurrence argmax (columns visited in increasing order).
    float m = -INFINITY;
    int   mi = NCLS;
    #pragma unroll
    for (int k = 0; k < 7; ++k) {
        const int base = (lane + 64 * k) * 4;
        const float* f = reinterpret_cast<const float*>(&v[k]);
        #pragma unroll
        for (int j = 0; j < 4; ++j) {
            if (f[j] > m) { m = f[j]; mi = base + j; }
        }
    }

    // Wave-wide argmax reduce; tie -> lowest index.
    #pragma unroll
    for (int off = 32; off > 0; off >>= 1) {
        const float om = __shfl_xor(m, off, 64);
        const int   oi = __shfl_xor(mi, off, 64);
        if (om > m || (om == m && oi < mi)) { m = om; mi = oi; }
    }

    // Sum of exp(v - m); padding lanes hold -inf -> exp -> 0.
    float s = 0.0f;
    #pragma unroll
    for (int k = 0; k < 7; ++k) {
        const float* f = reinterpret_cast<const float*>(&v[k]);
        #pragma unroll
        for (int j = 0; j < 4; ++j) {
            s += exp2f((f[j] - m) * LOG2E);
        }
    }
    #pragma unroll
    for (int off = 32; off > 0; off >>= 1) {
        s += __shfl_xor(s, off, 64);
    }

    __shared__ float part[4];
    __shared__ int lastFlag;
    if (lane == 0) {
        const float ce  = logf(s) + m - lt;            // -log_softmax at target
        const float pen = P[(size_t)tgt * NCLS + mi];  // penalty[target, argmax]
        part[wave] = ce + pen;
    }
    __syncthreads();

    if (threadIdx.x == 0) {
        const float partial = (part[0] + part[1]) + (part[2] + part[3]);
        // Agent-scope store: visible at the coherence point, no dirty L2 line.
        __hip_atomic_store(&ws[blockIdx.x], partial, __ATOMIC_RELAXED,
                           __HIP_MEMORY_SCOPE_AGENT);
        // Release: orders the ws store before the counter increment.
        const unsigned old = __hip_atomic_fetch_add(counter, 1u, __ATOMIC_RELEASE,
                                                    __HIP_MEMORY_SCOPE_AGENT);
        lastFlag = (old == NBLOCKS - 1);
    }
    __syncthreads();

    if (lastFlag) {
        // Acquire: invalidate stale L1/L2 so plain loads see all partials.
        __builtin_amdgcn_fence(__ATOMIC_ACQUIRE, "agent");
        float acc = 0.0f;
        const float4* __restrict__ wp = reinterpret_cast<const float4*>(ws);
        #pragma unroll
        for (int k = 0; k < 4; ++k) {
            const float4 t = wp[threadIdx.x + 256 * k];
            acc += (t.x + t.y) + (t.z + t.w);
        }
        #pragma unroll
        for (int off = 32; off > 0; off >>= 1) {
            acc += __shfl_xor(acc, off, 64);
        }
        __shared__ float sm[4];
        if (lane == 0) sm[wave] = acc;
        __syncthreads();
        if (threadIdx.x == 0) {
            out[0] = ((sm[0] + sm[1]) + (sm[2] + sm[3])) / (float)NBATCH;
        }
    }
}

extern "C" void kernel_launch(void* const* d_in, const int* in_sizes, int n_in,
                              void* d_out, int out_size, void* d_ws, size_t ws_size,
                              hipStream_t stream) {
    const float* logits  = (const float*)d_in[0];
    const int*   targets = (const int*)d_in[1];
    const float* P       = (const float*)d_in[2];
    float* out = (float*)d_out;
    float* ws  = (float*)d_ws;                       // 4096 floats = 16 KB
    unsigned* counter = (unsigned*)(ws + NBLOCKS);   // +4 bytes

    hipMemsetAsync(counter, 0, sizeof(unsigned), stream);
    cevp_fused_kernel<<<NBLOCKS, 256, 0, stream>>>(logits, targets, P, ws, counter, out);
}

// Round 4
// 26.375 us; speedup vs baseline: 4.6874x; 4.6874x over previous
//
#include <hip/hip_runtime.h>
#include <math.h>

#define NCLS 1784
#define NF4 446          // 1784 / 4
#define NBATCH 16384
#define NBLOCKS (NBATCH / 4)   // 4096
#define LOG2E 1.4426950408889634f

// One wave (64 lanes) per row; 4 rows per 256-thread block.
// Each block writes ONE partial (ce+penalty over its 4 rows) to ws.
__global__ __launch_bounds__(256) void cevp_row_kernel(
        const float* __restrict__ logits,
        const int* __restrict__ targets,
        const float* __restrict__ P,
        float* __restrict__ ws) {
    const int wave = threadIdx.x >> 6;          // 0..3
    const int lane = threadIdx.x & 63;
    const int row  = blockIdx.x * 4 + wave;

    // Hoisted scattered loads: latency overlaps the bulk row loads below.
    const int   tgt = targets[row];
    const float lt  = logits[(size_t)row * NCLS + tgt];

    const float4* __restrict__ rp =
        reinterpret_cast<const float4*>(logits + (size_t)row * NCLS);

    // Whole row into registers: 7 float4 per lane (446 f4 per row).
    float4 v[7];
    #pragma unroll
    for (int k = 0; k < 7; ++k) {
        const int idx = lane + 64 * k;
        if (idx < NF4) {
            v[k] = rp[idx];
        } else {
            v[k] = make_float4(-INFINITY, -INFINITY, -INFINITY, -INFINITY);
        }
    }

    // Per-lane max; track compact code = 4k+j (0..27, inline-const selects).
    // Scan order is ascending column index for a fixed lane -> '>' keeps
    // the first occurrence within the lane.
    float m = -INFINITY;
    int code = 0;
    #pragma unroll
    for (int k = 0; k < 7; ++k) {
        const float* f = reinterpret_cast<const float*>(&v[k]);
        #pragma unroll
        for (int j = 0; j < 4; ++j) {
            const bool gt = f[j] > m;
            code = gt ? (k * 4 + j) : code;
            m    = gt ? f[j]        : m;
        }
    }
    // True column index: idx = 256*k + 4*lane + j.
    int mi = ((code >> 2) << 8) + (lane << 2) + (code & 3);

    // Wave-wide argmax reduce; tie -> lowest index (matches jnp.argmax).
    #pragma unroll
    for (int off = 32; off > 0; off >>= 1) {
        const float om = __shfl_xor(m, off, 64);
        const int   oi = __shfl_xor(mi, off, 64);
        if (om > m || (om == m && oi < mi)) { m = om; mi = oi; }
    }

    // Sum of exp2(f*log2e + c); padding lanes hold -inf -> 0.
    // 4 independent accumulators: no serial add chain, pk-packable.
    const float c = -m * LOG2E;
    float s0 = 0.f, s1 = 0.f, s2 = 0.f, s3 = 0.f;
    #pragma unroll
    for (int k = 0; k < 7; ++k) {
        const float* f = reinterpret_cast<const float*>(&v[k]);
        s0 += exp2f(fmaf(f[0], LOG2E, c));
        s1 += exp2f(fmaf(f[1], LOG2E, c));
        s2 += exp2f(fmaf(f[2], LOG2E, c));
        s3 += exp2f(fmaf(f[3], LOG2E, c));
    }
    float s = (s0 + s1) + (s2 + s3);
    #pragma unroll
    for (int off = 32; off > 0; off >>= 1) {
        s += __shfl_xor(s, off, 64);
    }

    __shared__ float part[4];
    if (lane == 0) {
        const float ce  = logf(s) + m - lt;            // -log_softmax at target
        const float pen = P[(size_t)tgt * NCLS + mi];  // penalty[target, argmax]
        part[wave] = ce + pen;
    }
    __syncthreads();
    if (threadIdx.x == 0) {
        ws[blockIdx.x] = (part[0] + part[1]) + (part[2] + part[3]);
    }
}

// Deterministic reduction of 4096 block partials: one float4 per thread.
__global__ __launch_bounds__(1024) void cevp_reduce_kernel(
        const float* __restrict__ ws, float* __restrict__ out) {
    __shared__ float sm[16];
    const int tid = threadIdx.x;
    const float4 v = reinterpret_cast<const float4*>(ws)[tid];
    float s = (v.x + v.y) + (v.z + v.w);
    #pragma unroll
    for (int off = 32; off > 0; off >>= 1) {
        s += __shfl_xor(s, off, 64);
    }
    if ((tid & 63) == 0) sm[tid >> 6] = s;
    __syncthreads();
    if (tid < 16) {
        float t = sm[tid];
        #pragma unroll
        for (int off = 8; off > 0; off >>= 1) {
            t += __shfl_xor(t, off, 64);
        }
        if (tid == 0) out[0] = t / (float)NBATCH;
    }
}

extern "C" void kernel_launch(void* const* d_in, const int* in_sizes, int n_in,
                              void* d_out, int out_size, void* d_ws, size_t ws_size,
                              hipStream_t stream) {
    const float* logits  = (const float*)d_in[0];
    const int*   targets = (const int*)d_in[1];
    const float* P       = (const float*)d_in[2];
    float* out = (float*)d_out;
    float* ws  = (float*)d_ws;   // 4096 floats = 16 KB

    cevp_row_kernel<<<NBLOCKS, 256, 0, stream>>>(logits, targets, P, ws);
    cevp_reduce_kernel<<<1, 1024, 0, stream>>>(ws, out);
}